// Round 6
// baseline (295.114 us; speedup 1.0000x reference)
//
#include <hip/hip_runtime.h>
#include <cstdint>

typedef unsigned long long ull;
typedef __bf16 bf16x8 __attribute__((ext_vector_type(8)));
typedef float f32x4 __attribute__((ext_vector_type(4)));

#define NPTS 8192
#define NB 2
#define KNN 16
#define DM 128
#define PADK 136

__device__ __forceinline__ float sq3f(float x, float y, float z) {
    return __fadd_rn(__fadd_rn(__fmul_rn(x, x), __fmul_rn(y, y)), __fmul_rn(z, z));
}
__device__ __forceinline__ float dot3f(float ax, float ay, float az, float bx, float by, float bz) {
    return __fadd_rn(__fadd_rn(__fmul_rn(ax, bx), __fmul_rn(ay, by)), __fmul_rn(az, bz));
}
__device__ __forceinline__ unsigned ford(unsigned u) {
    return (u & 0x80000000u) ? ~u : (u | 0x80000000u);
}
__device__ __forceinline__ float inv_ford(unsigned f) {
    unsigned u = (f & 0x80000000u) ? (f ^ 0x80000000u) : ~f;
    return __uint_as_float(u);
}

// ---------------------------------------------------------------- KNN
// Wave-cooperative top-16, VALU-slimmed (R5 was VALU-issue-bound at 90%):
//  - hot-loop trigger is a single float compare d <= thrF (conservative
//    superset of the exact lexicographic test; inserts stay exact)
//  - 2 candidates per lane per ballot (half the loop/ballot overhead)
//  - ford/index math only on wave-uniform readlane'd scalars (SALU)
//  - staging via 3 coalesced float4 loads per thread
// Selection is bit-identical to jax.lax.top_k ((dist_bits, idx) ascending).
__global__ __launch_bounds__(256) void knn_kernel(const float* __restrict__ xyz,
                                                  int* __restrict__ idx_out) {
    __shared__ float4 xs4[1024];
    const int t = threadIdx.x;
    const int wv = t >> 6, lane = t & 63;
    const int q_id = blockIdx.x * 4 + wv;
    const int b = q_id >> 13;
    const int i = q_id & (NPTS - 1);
    const float* xb = xyz + (size_t)b * NPTS * 3;
    const float qx = xb[3 * i + 0], qy = xb[3 * i + 1], qz = xb[3 * i + 2];
    const float sqi = sq3f(qx, qy, qz);

    // lanes 0..15: sorted top-16 (ascending, lexicographic (ford(d), idx))
    unsigned list_hi = 0xffffffffu, list_lo = 0xffffffffu;
    float thrF = __uint_as_float(0x7f800000u);  // +inf until list is real

    for (int ch = 0; ch < 8; ++ch) {
        __syncthreads();
        {
            const float* src = xb + ch * 3072 + t * 12;
            float4 f0 = *(const float4*)(src);
            float4 f1 = *(const float4*)(src + 4);
            float4 f2 = *(const float4*)(src + 8);
            xs4[t * 4 + 0] = make_float4(f0.x, f0.y, f0.z, sq3f(f0.x, f0.y, f0.z));
            xs4[t * 4 + 1] = make_float4(f0.w, f1.x, f1.y, sq3f(f0.w, f1.x, f1.y));
            xs4[t * 4 + 2] = make_float4(f1.z, f1.w, f2.x, sq3f(f1.z, f1.w, f2.x));
            xs4[t * 4 + 3] = make_float4(f2.y, f2.z, f2.w, sq3f(f2.y, f2.z, f2.w));
        }
        __syncthreads();
        for (int m = 0; m < 8; m++) {
            const int jl = m * 128 + lane;
            float4 P = xs4[jl];
            float4 Q = xs4[jl + 64];
            float dA = __fsub_rn(__fadd_rn(sqi, P.w),
                                 __fmul_rn(2.0f, dot3f(qx, qy, qz, P.x, P.y, P.z)));
            float dB = __fsub_rn(__fadd_rn(sqi, Q.w),
                                 __fmul_rn(2.0f, dot3f(qx, qy, qz, Q.x, Q.y, Q.z)));
            bool ta = (dA <= thrF), tb = (dB <= thrF);
            ull ballot = __ballot(ta || tb);
            if (ballot == 0ull) continue;   // wave-uniform branch
            const unsigned jbase = (unsigned)(ch * 1024 + m * 128);
            do {
                int l = (int)__builtin_ctzll(ballot);
                ballot &= ballot - 1;
                float fA = __uint_as_float(
                    (unsigned)__builtin_amdgcn_readlane(__float_as_int(dA), l));
                float fB = __uint_as_float(
                    (unsigned)__builtin_amdgcn_readlane(__float_as_int(dB), l));
#pragma unroll
                for (int half = 0; half < 2; half++) {
                    float fc = half ? fB : fA;
                    if (fc <= thrF) {   // uniform guard vs current threshold
                        unsigned ck_hi = ford(__float_as_uint(fc));          // SALU
                        unsigned ck_lo = jbase + (unsigned)l + (half ? 64u : 0u);
                        unsigned ph = __shfl_up(list_hi, 1);
                        unsigned pl = __shfl_up(list_lo, 1);
                        bool lt = (ck_hi < list_hi) || (ck_hi == list_hi && ck_lo < list_lo);
                        bool ge = (lane == 0) || (ck_hi > ph) || (ck_hi == ph && ck_lo >= pl);
                        unsigned nh = ge ? ck_hi : ph;
                        unsigned nl = ge ? ck_lo : pl;
                        list_hi = lt ? nh : list_hi;
                        list_lo = lt ? nl : list_lo;
                        unsigned th = (unsigned)__builtin_amdgcn_readlane((int)list_hi, 15);
                        th = (th > 0xff800000u) ? 0xff800000u : th;  // sentinel -> +inf
                        thrF = inv_ford(th);
                    }
                }
            } while (ballot);
        }
    }
    if (lane < 16)
        idx_out[q_id * 16 + lane] = (int)list_lo;
}

// ---------------------------------------------------------------- weight prep: f32 [k][n] -> bf16 [n][k]
__global__ __launch_bounds__(256) void wprep_kernel(const float* __restrict__ d2,
                                                    const float* __restrict__ g1,
                                                    const float* __restrict__ g2,
                                                    __bf16* __restrict__ d2t,
                                                    __bf16* __restrict__ g1t,
                                                    __bf16* __restrict__ g2t) {
    const float* src = (blockIdx.x == 0) ? d2 : ((blockIdx.x == 1) ? g1 : g2);
    __bf16* dst = (blockIdx.x == 0) ? d2t : ((blockIdx.x == 1) ? g1t : g2t);
#pragma unroll
    for (int e = 0; e < 64; e++) {
        int id = threadIdx.x + e * 256;
        int k = id >> 7, n = id & 127;
        dst[n * 128 + k] = (__bf16)src[id];
    }
}

// ---------------------------------------------------------------- x = features@fc1 + b
__global__ __launch_bounds__(256, 1) void gemm_x_kernel(const float* __restrict__ feats,
                                                        const float* __restrict__ w,
                                                        const float* __restrict__ bias,
                                                        float* __restrict__ xout) {
    __shared__ float At[64 * 65];
    __shared__ __align__(16) float Wt[64 * 128];
    const int t = threadIdx.x;
    const int base = blockIdx.x * 64;
#pragma unroll
    for (int e = 0; e < 16; e++) {
        int id = t + e * 256;
        int r = id >> 6, c = id & 63;
        At[c * 65 + r] = feats[(size_t)(base + r) * 64 + c];
    }
#pragma unroll
    for (int e = 0; e < 32; e++) { int id = t + e * 256; Wt[id] = w[id]; }
    __syncthreads();
    const int r0 = (t >> 4) * 4;
    const int c0 = (t & 15) * 8;
    float acc[4][8];
#pragma unroll
    for (int i = 0; i < 4; i++)
#pragma unroll
        for (int j = 0; j < 8; j++) acc[i][j] = bias[c0 + j];
#pragma unroll 4
    for (int kk = 0; kk < 64; ++kk) {
        float a0 = At[kk * 65 + r0 + 0];
        float a1 = At[kk * 65 + r0 + 1];
        float a2 = At[kk * 65 + r0 + 2];
        float a3 = At[kk * 65 + r0 + 3];
        const float4 w0 = *(const float4*)&Wt[kk * 128 + c0];
        const float4 w1 = *(const float4*)&Wt[kk * 128 + c0 + 4];
        float wj[8] = {w0.x, w0.y, w0.z, w0.w, w1.x, w1.y, w1.z, w1.w};
#pragma unroll
        for (int j = 0; j < 8; j++) {
            acc[0][j] += a0 * wj[j];
            acc[1][j] += a1 * wj[j];
            acc[2][j] += a2 * wj[j];
            acc[3][j] += a3 * wj[j];
        }
    }
#pragma unroll
    for (int i = 0; i < 4; i++)
#pragma unroll
        for (int j = 0; j < 8; j++)
            xout[(size_t)(base + r0 + i) * 128 + c0 + j] = acc[i][j];
}

// ---------------------------------------------------------------- q/xk/xv = x@W (no bias)
__global__ __launch_bounds__(256, 1) void gemm_qkv_kernel(const float* __restrict__ x,
                                                          const float* __restrict__ wq,
                                                          const float* __restrict__ wk,
                                                          const float* __restrict__ wv,
                                                          float* __restrict__ qo,
                                                          float* __restrict__ ko,
                                                          float* __restrict__ vo) {
    const float* w = (blockIdx.y == 0) ? wq : ((blockIdx.y == 1) ? wk : wv);
    float* o = (blockIdx.y == 0) ? qo : ((blockIdx.y == 1) ? ko : vo);
    __shared__ float At[128 * 65];
    __shared__ __align__(16) float Wt[128 * 128];
    const int t = threadIdx.x;
    const int base = blockIdx.x * 64;
#pragma unroll
    for (int e = 0; e < 32; e++) {
        int id = t + e * 256;
        int r = id >> 7, c = id & 127;
        At[c * 65 + r] = x[(size_t)(base + r) * 128 + c];
    }
#pragma unroll
    for (int e = 0; e < 64; e++) { int id = t + e * 256; Wt[id] = w[id]; }
    __syncthreads();
    const int r0 = (t >> 4) * 4;
    const int c0 = (t & 15) * 8;
    float acc[4][8];
#pragma unroll
    for (int i = 0; i < 4; i++)
#pragma unroll
        for (int j = 0; j < 8; j++) acc[i][j] = 0.0f;
#pragma unroll 4
    for (int kk = 0; kk < 128; ++kk) {
        float a0 = At[kk * 65 + r0 + 0];
        float a1 = At[kk * 65 + r0 + 1];
        float a2 = At[kk * 65 + r0 + 2];
        float a3 = At[kk * 65 + r0 + 3];
        const float4 w0 = *(const float4*)&Wt[kk * 128 + c0];
        const float4 w1 = *(const float4*)&Wt[kk * 128 + c0 + 4];
        float wj[8] = {w0.x, w0.y, w0.z, w0.w, w1.x, w1.y, w1.z, w1.w};
#pragma unroll
        for (int j = 0; j < 8; j++) {
            acc[0][j] += a0 * wj[j];
            acc[1][j] += a1 * wj[j];
            acc[2][j] += a2 * wj[j];
            acc[3][j] += a3 * wj[j];
        }
    }
#pragma unroll
    for (int i = 0; i < 4; i++)
#pragma unroll
        for (int j = 0; j < 8; j++)
            o[(size_t)(base + r0 + i) * 128 + c0 + j] = acc[i][j];
}

// MFMA K-loop over K=128: contiguous-8-per-lane fragments (m91/m92-verified convention)
#define DO_GEMM(ACC0, ACC1, WPTR)                                                          \
    {                                                                                      \
        _Pragma("unroll")                                                                  \
        for (int kt = 0; kt < 4; kt++) {                                                   \
            const int ko = kt * 32 + 8 * lg;                                               \
            bf16x8 a0 = *(const bf16x8*)&Ab[(rbase + lr) * PADK + ko];                     \
            bf16x8 a1 = *(const bf16x8*)&Ab[(rbase + 16 + lr) * PADK + ko];                \
            _Pragma("unroll")                                                              \
            for (int ct = 0; ct < 8; ct++) {                                               \
                bf16x8 bv = *(const bf16x8*)&WPTR[(ct * 16 + lr) * PADK + ko];             \
                ACC0[ct] = __builtin_amdgcn_mfma_f32_16x16x32_bf16(a0, bv, ACC0[ct], 0, 0, 0); \
                ACC1[ct] = __builtin_amdgcn_mfma_f32_16x16x32_bf16(a1, bv, ACC1[ct], 0, 0, 0); \
            }                                                                              \
        }                                                                                  \
    }

#define STAGE_W(SRC)                                                                       \
    {                                                                                      \
        _Pragma("unroll")                                                                  \
        for (int e = 0; e < 8; e++) {                                                      \
            int ch = t + e * 256;                                                          \
            int r = ch >> 4, ck = ch & 15;                                                 \
            *(bf16x8*)&Wb[r * PADK + ck * 8] = *(const bf16x8*)&SRC[r * 128 + ck * 8];     \
        }                                                                                  \
    }

// ---------------------------------------------------------------- fused k3+k4+k5
__global__ __launch_bounds__(256, 2) void k345_kernel(const float* __restrict__ xyz,
                                                      const int* __restrict__ idxw,
                                                      const float* __restrict__ q,
                                                      const float* __restrict__ xk,
                                                      const float* __restrict__ xv,
                                                      const float* __restrict__ d1,
                                                      const float* __restrict__ bd1,
                                                      const float* __restrict__ bd2,
                                                      const float* __restrict__ bg1,
                                                      const float* __restrict__ bg2,
                                                      const __bf16* __restrict__ d2t,
                                                      const __bf16* __restrict__ g1t,
                                                      const __bf16* __restrict__ g2t,
                                                      float* __restrict__ attn,
                                                      float* __restrict__ res_pre) {
    __shared__ __bf16 Ab[128 * PADK];
    __shared__ __bf16 Wb[128 * PADK];
    __shared__ float rels[128 * 4];
    __shared__ int jrow[128];
    __shared__ float d1s[3 * 128];
    __shared__ float bd1s[128], bd2s[128], bg1s[128], bg2s[128];

    const int t = threadIdx.x;
    const int wv = t >> 6;
    const int lane = t & 63;
    const int lr = lane & 15, lg = lane >> 4;
    const int R0 = blockIdx.x * 128;
    const int b = R0 >> 17;
    const int rbase = wv * 32;

#pragma unroll
    for (int e = 0; e < 2; e++) { int id = t + e * 256; if (id < 384) d1s[id] = d1[id]; }
    if (t < 128) {
        bd1s[t] = bd1[t]; bd2s[t] = bd2[t]; bg1s[t] = bg1[t]; bg2s[t] = bg2[t];
    } else {
        int r = t - 128;
        int j = idxw[R0 + r];
        jrow[r] = j;
        const float* pn = xyz + (size_t)((R0 + r) >> 4) * 3;
        const float* pj = xyz + (size_t)((b << 13) + j) * 3;
        rels[r * 4 + 0] = pn[0] - pj[0];
        rels[r * 4 + 1] = pn[1] - pj[1];
        rels[r * 4 + 2] = pn[2] - pj[2];
    }
    STAGE_W(d2t)
    __syncthreads();

    // T = relu(rel@d1 + bd1) -> Ab (bf16)
    {
        const int c = t & 127;
        const float w0 = d1s[c], w1 = d1s[128 + c], w2 = d1s[256 + c], bb = bd1s[c];
#pragma unroll
        for (int e = 0; e < 64; e++) {
            int r = (t >> 7) + e * 2;
            float v = fmaf(rels[r * 4 + 2], w2,
                      fmaf(rels[r * 4 + 1], w1, fmaf(rels[r * 4 + 0], w0, bb)));
            Ab[r * PADK + c] = (__bf16)fmaxf(v, 0.0f);
        }
    }
    __syncthreads();

    // GEMM1: pos = relu(T@d2 + bd2), kept in registers for h AND the value path
    f32x4 acc0[8], acc1[8];
#pragma unroll
    for (int ct = 0; ct < 8; ct++) {
        float bb = bd2s[ct * 16 + lr];
        acc0[ct] = (f32x4){bb, bb, bb, bb};
        acc1[ct] = acc0[ct];
    }
    DO_GEMM(acc0, acc1, Wb)
    f32x4 pos0[8], pos1[8];
#pragma unroll
    for (int ct = 0; ct < 8; ct++) {
#pragma unroll
        for (int e = 0; e < 4; e++) {
            pos0[ct][e] = fmaxf(acc0[ct][e], 0.0f);
            pos1[ct][e] = fmaxf(acc1[ct][e], 0.0f);
        }
    }

    // h = pos + q - k_nbr  -> Ab (bf16)   [own rows only]
#pragma unroll
    for (int rt = 0; rt < 2; rt++) {
        const int rloc = rbase + rt * 16 + 4 * lg;
        const size_t qbase = (size_t)((R0 + rloc) >> 4) * 128;
        const int j0 = jrow[rloc + 0], j1 = jrow[rloc + 1];
        const int j2 = jrow[rloc + 2], j3 = jrow[rloc + 3];
        const size_t kb0 = (size_t)((b << 13) + j0) * 128;
        const size_t kb1 = (size_t)((b << 13) + j1) * 128;
        const size_t kb2 = (size_t)((b << 13) + j2) * 128;
        const size_t kb3 = (size_t)((b << 13) + j3) * 128;
        f32x4* posR = rt ? pos1 : pos0;
#pragma unroll
        for (int ct = 0; ct < 8; ct++) {
            const int c = ct * 16 + lr;
            const float qv = q[qbase + c];
            f32x4 p = posR[ct];
            Ab[(rloc + 0) * PADK + c] = (__bf16)(p[0] + qv - xk[kb0 + c]);
            Ab[(rloc + 1) * PADK + c] = (__bf16)(p[1] + qv - xk[kb1 + c]);
            Ab[(rloc + 2) * PADK + c] = (__bf16)(p[2] + qv - xk[kb2 + c]);
            Ab[(rloc + 3) * PADK + c] = (__bf16)(p[3] + qv - xk[kb3 + c]);
        }
    }
    __syncthreads();
    STAGE_W(g1t)
    __syncthreads();

    // GEMM2: u = relu(h@g1 + bg1) -> Ab (bf16)
#pragma unroll
    for (int ct = 0; ct < 8; ct++) {
        float bb = bg1s[ct * 16 + lr];
        acc0[ct] = (f32x4){bb, bb, bb, bb};
        acc1[ct] = acc0[ct];
    }
    DO_GEMM(acc0, acc1, Wb)
#pragma unroll
    for (int rt = 0; rt < 2; rt++) {
        const int rloc = rbase + rt * 16 + 4 * lg;
        f32x4* accR = rt ? acc1 : acc0;
#pragma unroll
        for (int ct = 0; ct < 8; ct++) {
            const int c = ct * 16 + lr;
            f32x4 p = accR[ct];
            Ab[(rloc + 0) * PADK + c] = (__bf16)fmaxf(p[0], 0.0f);
            Ab[(rloc + 1) * PADK + c] = (__bf16)fmaxf(p[1], 0.0f);
            Ab[(rloc + 2) * PADK + c] = (__bf16)fmaxf(p[2], 0.0f);
            Ab[(rloc + 3) * PADK + c] = (__bf16)fmaxf(p[3], 0.0f);
        }
    }
    __syncthreads();
    STAGE_W(g2t)
    __syncthreads();

    // GEMM3: logits = u@g2 + bg2 ; softmax over 16 neighbors ;
    // then res_pre = sum_k attn*(v+pos)
#pragma unroll
    for (int ct = 0; ct < 8; ct++) {
        float bb = bg2s[ct * 16 + lr];
        acc0[ct] = (f32x4){bb, bb, bb, bb};
        acc1[ct] = acc0[ct];
    }
    DO_GEMM(acc0, acc1, Wb)
    const float scale = 0.08838834764831845f; /* 1/sqrt(128) */
#pragma unroll
    for (int rt = 0; rt < 2; rt++) {
        const int rloc = rbase + rt * 16 + 4 * lg;
        const int j0 = jrow[rloc + 0], j1 = jrow[rloc + 1];
        const int j2 = jrow[rloc + 2], j3 = jrow[rloc + 3];
        const size_t vb0 = (size_t)((b << 13) + j0) * 128;
        const size_t vb1 = (size_t)((b << 13) + j1) * 128;
        const size_t vb2 = (size_t)((b << 13) + j2) * 128;
        const size_t vb3 = (size_t)((b << 13) + j3) * 128;
        f32x4* accR = rt ? acc1 : acc0;
        f32x4* posR = rt ? pos1 : pos0;
#pragma unroll
        for (int ct = 0; ct < 8; ct++) {
            const int c = ct * 16 + lr;
            f32x4 p = accR[ct];
            float l0 = p[0] * scale, l1 = p[1] * scale, l2 = p[2] * scale, l3 = p[3] * scale;
            float m = fmaxf(fmaxf(l0, l1), fmaxf(l2, l3));
            m = fmaxf(m, __shfl_xor(m, 16));
            m = fmaxf(m, __shfl_xor(m, 32));
            float e0 = __expf(l0 - m), e1 = __expf(l1 - m);
            float e2 = __expf(l2 - m), e3 = __expf(l3 - m);
            float s = (e0 + e1) + (e2 + e3);
            s += __shfl_xor(s, 16);
            s += __shfl_xor(s, 32);
            float inv = 1.0f / s;
            float a0 = e0 * inv, a1 = e1 * inv, a2 = e2 * inv, a3 = e3 * inv;
            size_t ob = (size_t)(R0 + rloc) * 128 + c;
            attn[ob + 0 * 128] = a0;
            attn[ob + 1 * 128] = a1;
            attn[ob + 2 * 128] = a2;
            attn[ob + 3 * 128] = a3;
            f32x4 pp = posR[ct];
            float r = a0 * (xv[vb0 + c] + pp[0])
                    + a1 * (xv[vb1 + c] + pp[1])
                    + a2 * (xv[vb2 + c] + pp[2])
                    + a3 * (xv[vb3 + c] + pp[3]);
            r += __shfl_xor(r, 16);
            r += __shfl_xor(r, 32);
            if (lg == 0)
                res_pre[(size_t)((R0 >> 4) + wv * 2 + rt) * 128 + c] = r;
        }
    }
}

// ---------------------------------------------------------------- res = res_pre@fc2 + b + features
__global__ __launch_bounds__(256, 1) void k6_kernel(const float* __restrict__ res_pre,
                                                    const float* __restrict__ w,
                                                    const float* __restrict__ bias,
                                                    const float* __restrict__ feats,
                                                    float* __restrict__ res_out) {
    __shared__ float At[128 * 65];
    __shared__ __align__(16) float Wt[128 * 64];
    const int t = threadIdx.x;
    const int base = blockIdx.x * 64;
#pragma unroll
    for (int e = 0; e < 32; e++) {
        int id = t + e * 256;
        int r = id >> 7, c = id & 127;
        At[c * 65 + r] = res_pre[(size_t)(base + r) * 128 + c];
    }
#pragma unroll
    for (int e = 0; e < 32; e++) { int id = t + e * 256; Wt[id] = w[id]; }
    __syncthreads();
    const int r0 = (t >> 4) * 4;
    const int c0 = (t & 15) * 4;
    float acc[4][4];
#pragma unroll
    for (int i = 0; i < 4; i++)
#pragma unroll
        for (int j = 0; j < 4; j++) acc[i][j] = bias[c0 + j];
#pragma unroll 4
    for (int kk = 0; kk < 128; ++kk) {
        float a0 = At[kk * 65 + r0 + 0];
        float a1 = At[kk * 65 + r0 + 1];
        float a2 = At[kk * 65 + r0 + 2];
        float a3 = At[kk * 65 + r0 + 3];
        const float4 w0 = *(const float4*)&Wt[kk * 64 + c0];
        float wj[4] = {w0.x, w0.y, w0.z, w0.w};
#pragma unroll
        for (int j = 0; j < 4; j++) {
            acc[0][j] += a0 * wj[j];
            acc[1][j] += a1 * wj[j];
            acc[2][j] += a2 * wj[j];
            acc[3][j] += a3 * wj[j];
        }
    }
#pragma unroll
    for (int i = 0; i < 4; i++)
#pragma unroll
        for (int j = 0; j < 4; j++)
            res_out[(size_t)(base + r0 + i) * 64 + c0 + j] =
                acc[i][j] + feats[(size_t)(base + r0 + i) * 64 + c0 + j];
}

extern "C" void kernel_launch(void* const* d_in, const int* in_sizes, int n_in,
                              void* d_out, int out_size, void* d_ws, size_t ws_size,
                              hipStream_t stream) {
    (void)in_sizes; (void)n_in; (void)out_size; (void)ws_size;
    const float* xyz   = (const float*)d_in[0];
    const float* feats = (const float*)d_in[2];
    const float* fc1_w = (const float*)d_in[3];
    const float* fc1_b = (const float*)d_in[4];
    const float* fc2_w = (const float*)d_in[5];
    const float* fc2_b = (const float*)d_in[6];
    const float* g1    = (const float*)d_in[7];
    const float* bg1   = (const float*)d_in[8];
    const float* g2    = (const float*)d_in[9];
    const float* bg2   = (const float*)d_in[10];
    const float* d1    = (const float*)d_in[11];
    const float* bd1   = (const float*)d_in[12];
    const float* d2    = (const float*)d_in[13];
    const float* bd2   = (const float*)d_in[14];
    const float* wq    = (const float*)d_in[15];
    const float* wk    = (const float*)d_in[16];
    const float* wv    = (const float*)d_in[17];

    int* idxw   = (int*)d_ws;
    float* xbuf = (float*)((char*)d_ws + (1 << 20));
    float* qbuf = xbuf + 2097152;
    float* kbuf = qbuf + 2097152;
    float* vbuf = kbuf + 2097152;
    float* rpre = vbuf + 2097152;
    __bf16* d2t = (__bf16*)(rpre + 2097152);
    __bf16* g1t = d2t + 16384;
    __bf16* g2t = g1t + 16384;

    float* res_out = (float*)d_out;
    float* attn    = res_out + 1048576;

    wprep_kernel<<<3, 256, 0, stream>>>(d2, g1, g2, d2t, g1t, g2t);
    knn_kernel<<<4096, 256, 0, stream>>>(xyz, idxw);
    gemm_x_kernel<<<256, 256, 0, stream>>>(feats, fc1_w, fc1_b, xbuf);
    gemm_qkv_kernel<<<dim3(256, 3), 256, 0, stream>>>(xbuf, wq, wk, wv, qbuf, kbuf, vbuf);
    k345_kernel<<<2048, 256, 0, stream>>>(xyz, idxw, qbuf, kbuf, vbuf, d1, bd1, bd2, bg1, bg2,
                                          d2t, g1t, g2t, attn, rpre);
    k6_kernel<<<256, 256, 0, stream>>>(rpre, fc2_w, fc2_b, feats, res_out);
}

// Round 7
// 285.939 us; speedup vs baseline: 1.0321x; 1.0321x over previous
//
#include <hip/hip_runtime.h>
#include <cstdint>

typedef unsigned long long ull;
typedef __bf16 bf16x8 __attribute__((ext_vector_type(8)));
typedef float f32x4 __attribute__((ext_vector_type(4)));

#define NPTS 8192
#define NB 2
#define KNN 16
#define DM 128
#define PADK 136

__device__ __forceinline__ float sq3f(float x, float y, float z) {
    return __fadd_rn(__fadd_rn(__fmul_rn(x, x), __fmul_rn(y, y)), __fmul_rn(z, z));
}
__device__ __forceinline__ float dot3f(float ax, float ay, float az, float bx, float by, float bz) {
    return __fadd_rn(__fadd_rn(__fmul_rn(ax, bx), __fmul_rn(ay, by)), __fmul_rn(az, bz));
}
__device__ __forceinline__ unsigned ford(unsigned u) {
    return (u & 0x80000000u) ? ~u : (u | 0x80000000u);
}
__device__ __forceinline__ float inv_ford(unsigned f) {
    unsigned u = (f & 0x80000000u) ? (f ^ 0x80000000u) : ~f;
    return __uint_as_float(u);
}

// ---------------------------------------------------------------- KNN
// Wave-cooperative top-16. R6 lesson: per-thread-consecutive float4 LDS
// writes are a ~32-way bank conflict (12.6M conflicts, VALUBusy 90->72).
// This round: R5's conflict-free staging (consecutive lanes -> consecutive
// float4s) + R6's slim hot loop (single float-compare trigger, 2 candidates
// per lane per ballot, readlane broadcast, SALU index math).
// Selection bit-identical to jax.lax.top_k ((dist_bits, idx) ascending).
__global__ __launch_bounds__(256) void knn_kernel(const float* __restrict__ xyz,
                                                  int* __restrict__ idx_out) {
    __shared__ float4 xs4[1024];
    const int t = threadIdx.x;
    const int wv = t >> 6, lane = t & 63;
    const int q_id = blockIdx.x * 4 + wv;
    const int b = q_id >> 13;
    const int i = q_id & (NPTS - 1);
    const float* xb = xyz + (size_t)b * NPTS * 3;
    const float qx = xb[3 * i + 0], qy = xb[3 * i + 1], qz = xb[3 * i + 2];
    const float sqi = sq3f(qx, qy, qz);

    // lanes 0..15: sorted top-16 (ascending, lexicographic (ford(d), idx))
    unsigned list_hi = 0xffffffffu, list_lo = 0xffffffffu;
    float thrF = __uint_as_float(0x7f800000u);  // +inf until list is real

    for (int ch = 0; ch < 8; ++ch) {
        __syncthreads();
#pragma unroll
        for (int e = 0; e < 4; e++) {
            int p = t + e * 256;
            int g = ch * 1024 + p;
            float x = xb[3 * g + 0], y = xb[3 * g + 1], z = xb[3 * g + 2];
            xs4[p] = make_float4(x, y, z, sq3f(x, y, z));   // lanes -> consecutive float4s: conflict-free
        }
        __syncthreads();
        for (int m = 0; m < 8; m++) {
            const int jl = m * 128 + lane;
            float4 P = xs4[jl];
            float4 Q = xs4[jl + 64];
            float dA = __fsub_rn(__fadd_rn(sqi, P.w),
                                 __fmul_rn(2.0f, dot3f(qx, qy, qz, P.x, P.y, P.z)));
            float dB = __fsub_rn(__fadd_rn(sqi, Q.w),
                                 __fmul_rn(2.0f, dot3f(qx, qy, qz, Q.x, Q.y, Q.z)));
            bool ta = (dA <= thrF), tb = (dB <= thrF);
            ull ballot = __ballot(ta || tb);
            if (ballot == 0ull) continue;   // wave-uniform branch
            const unsigned jbase = (unsigned)(ch * 1024 + m * 128);
            do {
                int l = (int)__builtin_ctzll(ballot);
                ballot &= ballot - 1;
                float fA = __uint_as_float(
                    (unsigned)__builtin_amdgcn_readlane(__float_as_int(dA), l));
                float fB = __uint_as_float(
                    (unsigned)__builtin_amdgcn_readlane(__float_as_int(dB), l));
#pragma unroll
                for (int half = 0; half < 2; half++) {
                    float fc = half ? fB : fA;
                    if (fc <= thrF) {   // uniform guard vs current threshold
                        unsigned ck_hi = ford(__float_as_uint(fc));          // SALU
                        unsigned ck_lo = jbase + (unsigned)l + (half ? 64u : 0u);
                        unsigned ph = __shfl_up(list_hi, 1);
                        unsigned pl = __shfl_up(list_lo, 1);
                        bool lt = (ck_hi < list_hi) || (ck_hi == list_hi && ck_lo < list_lo);
                        bool ge = (lane == 0) || (ck_hi > ph) || (ck_hi == ph && ck_lo >= pl);
                        unsigned nh = ge ? ck_hi : ph;
                        unsigned nl = ge ? ck_lo : pl;
                        list_hi = lt ? nh : list_hi;
                        list_lo = lt ? nl : list_lo;
                        unsigned th = (unsigned)__builtin_amdgcn_readlane((int)list_hi, 15);
                        th = (th > 0xff800000u) ? 0xff800000u : th;  // sentinel -> +inf
                        thrF = inv_ford(th);
                    }
                }
            } while (ballot);
        }
    }
    if (lane < 16)
        idx_out[q_id * 16 + lane] = (int)list_lo;
}

// ---------------------------------------------------------------- weight prep: f32 [k][n] -> bf16 [n][k]
__global__ __launch_bounds__(256) void wprep_kernel(const float* __restrict__ d2,
                                                    const float* __restrict__ g1,
                                                    const float* __restrict__ g2,
                                                    __bf16* __restrict__ d2t,
                                                    __bf16* __restrict__ g1t,
                                                    __bf16* __restrict__ g2t) {
    const float* src = (blockIdx.x == 0) ? d2 : ((blockIdx.x == 1) ? g1 : g2);
    __bf16* dst = (blockIdx.x == 0) ? d2t : ((blockIdx.x == 1) ? g1t : g2t);
#pragma unroll
    for (int e = 0; e < 64; e++) {
        int id = threadIdx.x + e * 256;
        int k = id >> 7, n = id & 127;
        dst[n * 128 + k] = (__bf16)src[id];
    }
}

// ---------------------------------------------------------------- x = features@fc1 + b
__global__ __launch_bounds__(256, 1) void gemm_x_kernel(const float* __restrict__ feats,
                                                        const float* __restrict__ w,
                                                        const float* __restrict__ bias,
                                                        float* __restrict__ xout) {
    __shared__ float At[64 * 65];
    __shared__ __align__(16) float Wt[64 * 128];
    const int t = threadIdx.x;
    const int base = blockIdx.x * 64;
#pragma unroll
    for (int e = 0; e < 16; e++) {
        int id = t + e * 256;
        int r = id >> 6, c = id & 63;
        At[c * 65 + r] = feats[(size_t)(base + r) * 64 + c];
    }
#pragma unroll
    for (int e = 0; e < 32; e++) { int id = t + e * 256; Wt[id] = w[id]; }
    __syncthreads();
    const int r0 = (t >> 4) * 4;
    const int c0 = (t & 15) * 8;
    float acc[4][8];
#pragma unroll
    for (int i = 0; i < 4; i++)
#pragma unroll
        for (int j = 0; j < 8; j++) acc[i][j] = bias[c0 + j];
#pragma unroll 4
    for (int kk = 0; kk < 64; ++kk) {
        float a0 = At[kk * 65 + r0 + 0];
        float a1 = At[kk * 65 + r0 + 1];
        float a2 = At[kk * 65 + r0 + 2];
        float a3 = At[kk * 65 + r0 + 3];
        const float4 w0 = *(const float4*)&Wt[kk * 128 + c0];
        const float4 w1 = *(const float4*)&Wt[kk * 128 + c0 + 4];
        float wj[8] = {w0.x, w0.y, w0.z, w0.w, w1.x, w1.y, w1.z, w1.w};
#pragma unroll
        for (int j = 0; j < 8; j++) {
            acc[0][j] += a0 * wj[j];
            acc[1][j] += a1 * wj[j];
            acc[2][j] += a2 * wj[j];
            acc[3][j] += a3 * wj[j];
        }
    }
#pragma unroll
    for (int i = 0; i < 4; i++)
#pragma unroll
        for (int j = 0; j < 8; j++)
            xout[(size_t)(base + r0 + i) * 128 + c0 + j] = acc[i][j];
}

// ---------------------------------------------------------------- q/xk/xv = x@W (no bias)
__global__ __launch_bounds__(256, 1) void gemm_qkv_kernel(const float* __restrict__ x,
                                                          const float* __restrict__ wq,
                                                          const float* __restrict__ wk,
                                                          const float* __restrict__ wv,
                                                          float* __restrict__ qo,
                                                          float* __restrict__ ko,
                                                          float* __restrict__ vo) {
    const float* w = (blockIdx.y == 0) ? wq : ((blockIdx.y == 1) ? wk : wv);
    float* o = (blockIdx.y == 0) ? qo : ((blockIdx.y == 1) ? ko : vo);
    __shared__ float At[128 * 65];
    __shared__ __align__(16) float Wt[128 * 128];
    const int t = threadIdx.x;
    const int base = blockIdx.x * 64;
#pragma unroll
    for (int e = 0; e < 32; e++) {
        int id = t + e * 256;
        int r = id >> 7, c = id & 127;
        At[c * 65 + r] = x[(size_t)(base + r) * 128 + c];
    }
#pragma unroll
    for (int e = 0; e < 64; e++) { int id = t + e * 256; Wt[id] = w[id]; }
    __syncthreads();
    const int r0 = (t >> 4) * 4;
    const int c0 = (t & 15) * 8;
    float acc[4][8];
#pragma unroll
    for (int i = 0; i < 4; i++)
#pragma unroll
        for (int j = 0; j < 8; j++) acc[i][j] = 0.0f;
#pragma unroll 4
    for (int kk = 0; kk < 128; ++kk) {
        float a0 = At[kk * 65 + r0 + 0];
        float a1 = At[kk * 65 + r0 + 1];
        float a2 = At[kk * 65 + r0 + 2];
        float a3 = At[kk * 65 + r0 + 3];
        const float4 w0 = *(const float4*)&Wt[kk * 128 + c0];
        const float4 w1 = *(const float4*)&Wt[kk * 128 + c0 + 4];
        float wj[8] = {w0.x, w0.y, w0.z, w0.w, w1.x, w1.y, w1.z, w1.w};
#pragma unroll
        for (int j = 0; j < 8; j++) {
            acc[0][j] += a0 * wj[j];
            acc[1][j] += a1 * wj[j];
            acc[2][j] += a2 * wj[j];
            acc[3][j] += a3 * wj[j];
        }
    }
#pragma unroll
    for (int i = 0; i < 4; i++)
#pragma unroll
        for (int j = 0; j < 8; j++)
            o[(size_t)(base + r0 + i) * 128 + c0 + j] = acc[i][j];
}

// MFMA K-loop over K=128: contiguous-8-per-lane fragments (m91/m92-verified convention)
#define DO_GEMM(ACC0, ACC1, WPTR)                                                          \
    {                                                                                      \
        _Pragma("unroll")                                                                  \
        for (int kt = 0; kt < 4; kt++) {                                                   \
            const int ko = kt * 32 + 8 * lg;                                               \
            bf16x8 a0 = *(const bf16x8*)&Ab[(rbase + lr) * PADK + ko];                     \
            bf16x8 a1 = *(const bf16x8*)&Ab[(rbase + 16 + lr) * PADK + ko];                \
            _Pragma("unroll")                                                              \
            for (int ct = 0; ct < 8; ct++) {                                               \
                bf16x8 bv = *(const bf16x8*)&WPTR[(ct * 16 + lr) * PADK + ko];             \
                ACC0[ct] = __builtin_amdgcn_mfma_f32_16x16x32_bf16(a0, bv, ACC0[ct], 0, 0, 0); \
                ACC1[ct] = __builtin_amdgcn_mfma_f32_16x16x32_bf16(a1, bv, ACC1[ct], 0, 0, 0); \
            }                                                                              \
        }                                                                                  \
    }

#define STAGE_W(SRC)                                                                       \
    {                                                                                      \
        _Pragma("unroll")                                                                  \
        for (int e = 0; e < 8; e++) {                                                      \
            int ch = t + e * 256;                                                          \
            int r = ch >> 4, ck = ch & 15;                                                 \
            *(bf16x8*)&Wb[r * PADK + ck * 8] = *(const bf16x8*)&SRC[r * 128 + ck * 8];     \
        }                                                                                  \
    }

// ---------------------------------------------------------------- fused k3+k4+k5
__global__ __launch_bounds__(256, 2) void k345_kernel(const float* __restrict__ xyz,
                                                      const int* __restrict__ idxw,
                                                      const float* __restrict__ q,
                                                      const float* __restrict__ xk,
                                                      const float* __restrict__ xv,
                                                      const float* __restrict__ d1,
                                                      const float* __restrict__ bd1,
                                                      const float* __restrict__ bd2,
                                                      const float* __restrict__ bg1,
                                                      const float* __restrict__ bg2,
                                                      const __bf16* __restrict__ d2t,
                                                      const __bf16* __restrict__ g1t,
                                                      const __bf16* __restrict__ g2t,
                                                      float* __restrict__ attn,
                                                      float* __restrict__ res_pre) {
    __shared__ __bf16 Ab[128 * PADK];
    __shared__ __bf16 Wb[128 * PADK];
    __shared__ float rels[128 * 4];
    __shared__ int jrow[128];
    __shared__ float d1s[3 * 128];
    __shared__ float bd1s[128], bd2s[128], bg1s[128], bg2s[128];

    const int t = threadIdx.x;
    const int wv = t >> 6;
    const int lane = t & 63;
    const int lr = lane & 15, lg = lane >> 4;
    const int R0 = blockIdx.x * 128;
    const int b = R0 >> 17;
    const int rbase = wv * 32;

#pragma unroll
    for (int e = 0; e < 2; e++) { int id = t + e * 256; if (id < 384) d1s[id] = d1[id]; }
    if (t < 128) {
        bd1s[t] = bd1[t]; bd2s[t] = bd2[t]; bg1s[t] = bg1[t]; bg2s[t] = bg2[t];
    } else {
        int r = t - 128;
        int j = idxw[R0 + r];
        jrow[r] = j;
        const float* pn = xyz + (size_t)((R0 + r) >> 4) * 3;
        const float* pj = xyz + (size_t)((b << 13) + j) * 3;
        rels[r * 4 + 0] = pn[0] - pj[0];
        rels[r * 4 + 1] = pn[1] - pj[1];
        rels[r * 4 + 2] = pn[2] - pj[2];
    }
    STAGE_W(d2t)
    __syncthreads();

    // T = relu(rel@d1 + bd1) -> Ab (bf16)
    {
        const int c = t & 127;
        const float w0 = d1s[c], w1 = d1s[128 + c], w2 = d1s[256 + c], bb = bd1s[c];
#pragma unroll
        for (int e = 0; e < 64; e++) {
            int r = (t >> 7) + e * 2;
            float v = fmaf(rels[r * 4 + 2], w2,
                      fmaf(rels[r * 4 + 1], w1, fmaf(rels[r * 4 + 0], w0, bb)));
            Ab[r * PADK + c] = (__bf16)fmaxf(v, 0.0f);
        }
    }
    __syncthreads();

    // GEMM1: pos = relu(T@d2 + bd2), kept in registers for h AND the value path
    f32x4 acc0[8], acc1[8];
#pragma unroll
    for (int ct = 0; ct < 8; ct++) {
        float bb = bd2s[ct * 16 + lr];
        acc0[ct] = (f32x4){bb, bb, bb, bb};
        acc1[ct] = acc0[ct];
    }
    DO_GEMM(acc0, acc1, Wb)
    f32x4 pos0[8], pos1[8];
#pragma unroll
    for (int ct = 0; ct < 8; ct++) {
#pragma unroll
        for (int e = 0; e < 4; e++) {
            pos0[ct][e] = fmaxf(acc0[ct][e], 0.0f);
            pos1[ct][e] = fmaxf(acc1[ct][e], 0.0f);
        }
    }

    // h = pos + q - k_nbr  -> Ab (bf16)   [own rows only]
#pragma unroll
    for (int rt = 0; rt < 2; rt++) {
        const int rloc = rbase + rt * 16 + 4 * lg;
        const size_t qbase = (size_t)((R0 + rloc) >> 4) * 128;
        const int j0 = jrow[rloc + 0], j1 = jrow[rloc + 1];
        const int j2 = jrow[rloc + 2], j3 = jrow[rloc + 3];
        const size_t kb0 = (size_t)((b << 13) + j0) * 128;
        const size_t kb1 = (size_t)((b << 13) + j1) * 128;
        const size_t kb2 = (size_t)((b << 13) + j2) * 128;
        const size_t kb3 = (size_t)((b << 13) + j3) * 128;
        f32x4* posR = rt ? pos1 : pos0;
#pragma unroll
        for (int ct = 0; ct < 8; ct++) {
            const int c = ct * 16 + lr;
            const float qv = q[qbase + c];
            f32x4 p = posR[ct];
            Ab[(rloc + 0) * PADK + c] = (__bf16)(p[0] + qv - xk[kb0 + c]);
            Ab[(rloc + 1) * PADK + c] = (__bf16)(p[1] + qv - xk[kb1 + c]);
            Ab[(rloc + 2) * PADK + c] = (__bf16)(p[2] + qv - xk[kb2 + c]);
            Ab[(rloc + 3) * PADK + c] = (__bf16)(p[3] + qv - xk[kb3 + c]);
        }
    }
    __syncthreads();
    STAGE_W(g1t)
    __syncthreads();

    // GEMM2: u = relu(h@g1 + bg1) -> Ab (bf16)
#pragma unroll
    for (int ct = 0; ct < 8; ct++) {
        float bb = bg1s[ct * 16 + lr];
        acc0[ct] = (f32x4){bb, bb, bb, bb};
        acc1[ct] = acc0[ct];
    }
    DO_GEMM(acc0, acc1, Wb)
#pragma unroll
    for (int rt = 0; rt < 2; rt++) {
        const int rloc = rbase + rt * 16 + 4 * lg;
        f32x4* accR = rt ? acc1 : acc0;
#pragma unroll
        for (int ct = 0; ct < 8; ct++) {
            const int c = ct * 16 + lr;
            f32x4 p = accR[ct];
            Ab[(rloc + 0) * PADK + c] = (__bf16)fmaxf(p[0], 0.0f);
            Ab[(rloc + 1) * PADK + c] = (__bf16)fmaxf(p[1], 0.0f);
            Ab[(rloc + 2) * PADK + c] = (__bf16)fmaxf(p[2], 0.0f);
            Ab[(rloc + 3) * PADK + c] = (__bf16)fmaxf(p[3], 0.0f);
        }
    }
    __syncthreads();
    STAGE_W(g2t)
    __syncthreads();

    // GEMM3: logits = u@g2 + bg2 ; softmax over 16 neighbors ;
    // then res_pre = sum_k attn*(v+pos)
#pragma unroll
    for (int ct = 0; ct < 8; ct++) {
        float bb = bg2s[ct * 16 + lr];
        acc0[ct] = (f32x4){bb, bb, bb, bb};
        acc1[ct] = acc0[ct];
    }
    DO_GEMM(acc0, acc1, Wb)
    const float scale = 0.08838834764831845f; /* 1/sqrt(128) */
#pragma unroll
    for (int rt = 0; rt < 2; rt++) {
        const int rloc = rbase + rt * 16 + 4 * lg;
        const int j0 = jrow[rloc + 0], j1 = jrow[rloc + 1];
        const int j2 = jrow[rloc + 2], j3 = jrow[rloc + 3];
        const size_t vb0 = (size_t)((b << 13) + j0) * 128;
        const size_t vb1 = (size_t)((b << 13) + j1) * 128;
        const size_t vb2 = (size_t)((b << 13) + j2) * 128;
        const size_t vb3 = (size_t)((b << 13) + j3) * 128;
        f32x4* accR = rt ? acc1 : acc0;
        f32x4* posR = rt ? pos1 : pos0;
#pragma unroll
        for (int ct = 0; ct < 8; ct++) {
            const int c = ct * 16 + lr;
            f32x4 p = accR[ct];
            float l0 = p[0] * scale, l1 = p[1] * scale, l2 = p[2] * scale, l3 = p[3] * scale;
            float m = fmaxf(fmaxf(l0, l1), fmaxf(l2, l3));
            m = fmaxf(m, __shfl_xor(m, 16));
            m = fmaxf(m, __shfl_xor(m, 32));
            float e0 = __expf(l0 - m), e1 = __expf(l1 - m);
            float e2 = __expf(l2 - m), e3 = __expf(l3 - m);
            float s = (e0 + e1) + (e2 + e3);
            s += __shfl_xor(s, 16);
            s += __shfl_xor(s, 32);
            float inv = 1.0f / s;
            float a0 = e0 * inv, a1 = e1 * inv, a2 = e2 * inv, a3 = e3 * inv;
            size_t ob = (size_t)(R0 + rloc) * 128 + c;
            attn[ob + 0 * 128] = a0;
            attn[ob + 1 * 128] = a1;
            attn[ob + 2 * 128] = a2;
            attn[ob + 3 * 128] = a3;
            f32x4 pp = posR[ct];
            float r = a0 * (xv[vb0 + c] + pp[0])
                    + a1 * (xv[vb1 + c] + pp[1])
                    + a2 * (xv[vb2 + c] + pp[2])
                    + a3 * (xv[vb3 + c] + pp[3]);
            r += __shfl_xor(r, 16);
            r += __shfl_xor(r, 32);
            if (lg == 0)
                res_pre[(size_t)((R0 >> 4) + wv * 2 + rt) * 128 + c] = r;
        }
    }
}

// ---------------------------------------------------------------- res = res_pre@fc2 + b + features
__global__ __launch_bounds__(256, 1) void k6_kernel(const float* __restrict__ res_pre,
                                                    const float* __restrict__ w,
                                                    const float* __restrict__ bias,
                                                    const float* __restrict__ feats,
                                                    float* __restrict__ res_out) {
    __shared__ float At[128 * 65];
    __shared__ __align__(16) float Wt[128 * 64];
    const int t = threadIdx.x;
    const int base = blockIdx.x * 64;
#pragma unroll
    for (int e = 0; e < 32; e++) {
        int id = t + e * 256;
        int r = id >> 7, c = id & 127;
        At[c * 65 + r] = res_pre[(size_t)(base + r) * 128 + c];
    }
#pragma unroll
    for (int e = 0; e < 32; e++) { int id = t + e * 256; Wt[id] = w[id]; }
    __syncthreads();
    const int r0 = (t >> 4) * 4;
    const int c0 = (t & 15) * 4;
    float acc[4][4];
#pragma unroll
    for (int i = 0; i < 4; i++)
#pragma unroll
        for (int j = 0; j < 4; j++) acc[i][j] = bias[c0 + j];
#pragma unroll 4
    for (int kk = 0; kk < 128; ++kk) {
        float a0 = At[kk * 65 + r0 + 0];
        float a1 = At[kk * 65 + r0 + 1];
        float a2 = At[kk * 65 + r0 + 2];
        float a3 = At[kk * 65 + r0 + 3];
        const float4 w0 = *(const float4*)&Wt[kk * 64 + c0];
        float wj[4] = {w0.x, w0.y, w0.z, w0.w};
#pragma unroll
        for (int j = 0; j < 4; j++) {
            acc[0][j] += a0 * wj[j];
            acc[1][j] += a1 * wj[j];
            acc[2][j] += a2 * wj[j];
            acc[3][j] += a3 * wj[j];
        }
    }
#pragma unroll
    for (int i = 0; i < 4; i++)
#pragma unroll
        for (int j = 0; j < 4; j++)
            res_out[(size_t)(base + r0 + i) * 64 + c0 + j] =
                acc[i][j] + feats[(size_t)(base + r0 + i) * 64 + c0 + j];
}

extern "C" void kernel_launch(void* const* d_in, const int* in_sizes, int n_in,
                              void* d_out, int out_size, void* d_ws, size_t ws_size,
                              hipStream_t stream) {
    (void)in_sizes; (void)n_in; (void)out_size; (void)ws_size;
    const float* xyz   = (const float*)d_in[0];
    const float* feats = (const float*)d_in[2];
    const float* fc1_w = (const float*)d_in[3];
    const float* fc1_b = (const float*)d_in[4];
    const float* fc2_w = (const float*)d_in[5];
    const float* fc2_b = (const float*)d_in[6];
    const float* g1    = (const float*)d_in[7];
    const float* bg1   = (const float*)d_in[8];
    const float* g2    = (const float*)d_in[9];
    const float* bg2   = (const float*)d_in[10];
    const float* d1    = (const float*)d_in[11];
    const float* bd1   = (const float*)d_in[12];
    const float* d2    = (const float*)d_in[13];
    const float* bd2   = (const float*)d_in[14];
    const float* wq    = (const float*)d_in[15];
    const float* wk    = (const float*)d_in[16];
    const float* wv    = (const float*)d_in[17];

    int* idxw   = (int*)d_ws;
    float* xbuf = (float*)((char*)d_ws + (1 << 20));
    float* qbuf = xbuf + 2097152;
    float* kbuf = qbuf + 2097152;
    float* vbuf = kbuf + 2097152;
    float* rpre = vbuf + 2097152;
    __bf16* d2t = (__bf16*)(rpre + 2097152);
    __bf16* g1t = d2t + 16384;
    __bf16* g2t = g1t + 16384;

    float* res_out = (float*)d_out;
    float* attn    = res_out + 1048576;

    wprep_kernel<<<3, 256, 0, stream>>>(d2, g1, g2, d2t, g1t, g2t);
    knn_kernel<<<4096, 256, 0, stream>>>(xyz, idxw);
    gemm_x_kernel<<<256, 256, 0, stream>>>(feats, fc1_w, fc1_b, xbuf);
    gemm_qkv_kernel<<<dim3(256, 3), 256, 0, stream>>>(xbuf, wq, wk, wv, qbuf, kbuf, vbuf);
    k345_kernel<<<2048, 256, 0, stream>>>(xyz, idxw, qbuf, kbuf, vbuf, d1, bd1, bd2, bg1, bg2,
                                          d2t, g1t, g2t, attn, rpre);
    k6_kernel<<<256, 256, 0, stream>>>(rpre, fc2_w, fc2_b, feats, res_out);
}

// Round 8
// 244.208 us; speedup vs baseline: 1.2085x; 1.1709x over previous
//
#include <hip/hip_runtime.h>
#include <cstdint>

typedef unsigned long long ull;
typedef __bf16 bf16x8 __attribute__((ext_vector_type(8)));
typedef float f32x4 __attribute__((ext_vector_type(4)));

#define NPTS 8192
#define NB 2
#define KNN 16
#define DM 128
#define PADK 136

__device__ __forceinline__ float sq3f(float x, float y, float z) {
    return __fadd_rn(__fadd_rn(__fmul_rn(x, x), __fmul_rn(y, y)), __fmul_rn(z, z));
}
__device__ __forceinline__ float dot3f(float ax, float ay, float az, float bx, float by, float bz) {
    return __fadd_rn(__fadd_rn(__fmul_rn(ax, bx), __fmul_rn(ay, by)), __fmul_rn(az, bz));
}
__device__ __forceinline__ unsigned ford(unsigned u) {
    return (u & 0x80000000u) ? ~u : (u | 0x80000000u);
}
__device__ __forceinline__ float inv_ford(unsigned f) {
    unsigned u = (f & 0x80000000u) ? (f ^ 0x80000000u) : ~f;
    return __uint_as_float(u);
}

// ---------------------------------------------------------------- KNN
// Wave-cooperative top-16. R7 analysis: pops (serial inserts) ~40% of VALU
// work, and the thr=+inf first batch alone is 64 of ~140 pops. This round:
//  - seed threshold before the first ballot: max over 16 disjoint 4-lane
//    groups of (min of that group's 8 candidates) >= true 16th of batch 0,
//    so skipping d > seed is exact. Kills the burn-in storm.
//  - thrF min-accumulates (upper-bound invariant; exact).
//  - separate A/B ballots: 1 readlane per pop.
// Selection bit-identical to jax.lax.top_k ((dist_bits, idx) ascending).
__global__ __launch_bounds__(256) void knn_kernel(const float* __restrict__ xyz,
                                                  int* __restrict__ idx_out) {
    __shared__ float4 xs4[1024];
    const int t = threadIdx.x;
    const int wv = t >> 6, lane = t & 63;
    const int q_id = blockIdx.x * 4 + wv;
    const int b = q_id >> 13;
    const int i = q_id & (NPTS - 1);
    const float* xb = xyz + (size_t)b * NPTS * 3;
    const float qx = xb[3 * i + 0], qy = xb[3 * i + 1], qz = xb[3 * i + 2];
    const float sqi = sq3f(qx, qy, qz);

    // lanes 0..15: sorted top-16 (ascending, lexicographic (ford(d), idx))
    unsigned list_hi = 0xffffffffu, list_lo = 0xffffffffu;
    float thrF = __uint_as_float(0x7f800000u);  // upper bound on current 16th

#define INSERT(FC, CKLO)                                                                 \
    {                                                                                    \
        unsigned ck_hi = ford(__float_as_uint(FC));                                      \
        unsigned ck_lo = (CKLO);                                                         \
        unsigned ph = __shfl_up(list_hi, 1);                                             \
        unsigned pl = __shfl_up(list_lo, 1);                                             \
        bool lt = (ck_hi < list_hi) || (ck_hi == list_hi && ck_lo < list_lo);            \
        bool ge = (lane == 0) || (ck_hi > ph) || (ck_hi == ph && ck_lo >= pl);           \
        list_hi = lt ? (ge ? ck_hi : ph) : list_hi;                                      \
        list_lo = lt ? (ge ? ck_lo : pl) : list_lo;                                      \
        unsigned th = (unsigned)__builtin_amdgcn_readlane((int)list_hi, 15);             \
        th = (th > 0xff800000u) ? 0xff800000u : th; /* sentinel/NaN -> +inf */           \
        thrF = fminf(thrF, inv_ford(th));                                                \
    }

    for (int ch = 0; ch < 8; ++ch) {
        __syncthreads();
#pragma unroll
        for (int e = 0; e < 4; e++) {
            int p = t + e * 256;
            int g = ch * 1024 + p;
            float x = xb[3 * g + 0], y = xb[3 * g + 1], z = xb[3 * g + 2];
            xs4[p] = make_float4(x, y, z, sq3f(x, y, z));  // consecutive lanes -> consecutive float4s
        }
        __syncthreads();
        for (int m = 0; m < 8; m++) {
            const int jl = m * 128 + lane;
            float4 P = xs4[jl];
            float4 Q = xs4[jl + 64];
            float dA = __fsub_rn(__fadd_rn(sqi, P.w),
                                 __fmul_rn(2.0f, dot3f(qx, qy, qz, P.x, P.y, P.z)));
            float dB = __fsub_rn(__fadd_rn(sqi, Q.w),
                                 __fmul_rn(2.0f, dot3f(qx, qy, qz, Q.x, Q.y, Q.z)));
            if (ch == 0 && m == 0) {
                // seed: max over 16 disjoint 4-lane-group minima (8 cands each)
                // >= 16th smallest of this batch -> exact to prune above it
                float mn = fminf(dA, dB);
                mn = fminf(mn, __shfl_xor(mn, 1));
                mn = fminf(mn, __shfl_xor(mn, 2));
                float mx = mn;
                mx = fmaxf(mx, __shfl_xor(mx, 4));
                mx = fmaxf(mx, __shfl_xor(mx, 8));
                mx = fmaxf(mx, __shfl_xor(mx, 16));
                mx = fmaxf(mx, __shfl_xor(mx, 32));
                thrF = mx;
            }
            ull balA = __ballot(dA <= thrF);
            ull balB = __ballot(dB <= thrF);
            if ((balA | balB) == 0ull) continue;   // wave-uniform branch
            const unsigned jbase = (unsigned)(ch * 1024 + m * 128);
            while (balA) {
                int l = (int)__builtin_ctzll(balA);
                balA &= balA - 1;
                float fc = __uint_as_float(
                    (unsigned)__builtin_amdgcn_readlane(__float_as_int(dA), l));
                if (fc <= thrF) INSERT(fc, jbase + (unsigned)l)
            }
            while (balB) {
                int l = (int)__builtin_ctzll(balB);
                balB &= balB - 1;
                float fc = __uint_as_float(
                    (unsigned)__builtin_amdgcn_readlane(__float_as_int(dB), l));
                if (fc <= thrF) INSERT(fc, jbase + 64u + (unsigned)l)
            }
        }
    }
#undef INSERT
    if (lane < 16)
        idx_out[q_id * 16 + lane] = (int)list_lo;
}

// ---------------------------------------------------------------- weight prep: f32 [k][n] -> bf16 [n][k]
__global__ __launch_bounds__(256) void wprep_kernel(const float* __restrict__ d2,
                                                    const float* __restrict__ g1,
                                                    const float* __restrict__ g2,
                                                    const float* __restrict__ wq,
                                                    const float* __restrict__ wk,
                                                    const float* __restrict__ wv,
                                                    __bf16* __restrict__ d2t,
                                                    __bf16* __restrict__ g1t,
                                                    __bf16* __restrict__ g2t,
                                                    __bf16* __restrict__ wqt,
                                                    __bf16* __restrict__ wkt,
                                                    __bf16* __restrict__ wvt) {
    const int bi = blockIdx.x;
    const float* src = (bi == 0) ? d2 : (bi == 1) ? g1 : (bi == 2) ? g2
                     : (bi == 3) ? wq : (bi == 4) ? wk : wv;
    __bf16* dst = (bi == 0) ? d2t : (bi == 1) ? g1t : (bi == 2) ? g2t
                : (bi == 3) ? wqt : (bi == 4) ? wkt : wvt;
#pragma unroll
    for (int e = 0; e < 64; e++) {
        int id = threadIdx.x + e * 256;
        int k = id >> 7, n = id & 127;
        dst[n * 128 + k] = (__bf16)src[id];
    }
}

#define STAGE_W(SRC)                                                                       \
    {                                                                                      \
        _Pragma("unroll")                                                                  \
        for (int e = 0; e < 8; e++) {                                                      \
            int ch = t + e * 256;                                                          \
            int r = ch >> 4, ck = ch & 15;                                                 \
            *(bf16x8*)&Wb[r * PADK + ck * 8] = *(const bf16x8*)&SRC[r * 128 + ck * 8];     \
        }                                                                                  \
    }

// ---------------------------------------------------------------- fused x + q/k/v:
// x = feats@fc1 + b (f32 VALU, K=64) -> bf16 LDS tile -> 3 MFMA GEMMs
// (wq, wk, wv) -> q/k/v f32 in ws. x never hits global memory.
__global__ __launch_bounds__(256, 1) void xqkv_kernel(const float* __restrict__ feats,
                                                      const float* __restrict__ fc1_w,
                                                      const float* __restrict__ fc1_b,
                                                      const __bf16* __restrict__ wqt,
                                                      const __bf16* __restrict__ wkt,
                                                      const __bf16* __restrict__ wvt,
                                                      float* __restrict__ qo,
                                                      float* __restrict__ ko,
                                                      float* __restrict__ vo) {
    __shared__ __align__(16) char lds[52224];
    float* At = (float*)lds;                 // [64 cols][65 rows] f32 (phase A)
    float* Wt = (float*)(lds + 16640);       // [64][128] f32 (phase A)
    __bf16* Ab = (__bf16*)lds;               // [64][PADK] bf16 (phase B)
    __bf16* Wb = (__bf16*)(lds + 17408);     // [128][PADK] bf16 (phase B)
    const int t = threadIdx.x;
    const int base = blockIdx.x * 64;

    // ---- phase A: x = feats@fc1 + b (f32)
#pragma unroll
    for (int e = 0; e < 16; e++) {
        int id = t + e * 256;
        int r = id >> 6, c = id & 63;
        At[c * 65 + r] = feats[(size_t)(base + r) * 64 + c];
    }
#pragma unroll
    for (int e = 0; e < 32; e++) { int id = t + e * 256; Wt[id] = fc1_w[id]; }
    __syncthreads();
    const int r0 = (t >> 4) * 4;
    const int c0 = (t & 15) * 8;
    float acc[4][8];
#pragma unroll
    for (int i = 0; i < 4; i++)
#pragma unroll
        for (int j = 0; j < 8; j++) acc[i][j] = fc1_b[c0 + j];
#pragma unroll 4
    for (int kk = 0; kk < 64; ++kk) {
        float a0 = At[kk * 65 + r0 + 0];
        float a1 = At[kk * 65 + r0 + 1];
        float a2 = At[kk * 65 + r0 + 2];
        float a3 = At[kk * 65 + r0 + 3];
        const float4 w0 = *(const float4*)&Wt[kk * 128 + c0];
        const float4 w1 = *(const float4*)&Wt[kk * 128 + c0 + 4];
        float wj[8] = {w0.x, w0.y, w0.z, w0.w, w1.x, w1.y, w1.z, w1.w};
#pragma unroll
        for (int j = 0; j < 8; j++) {
            acc[0][j] += a0 * wj[j];
            acc[1][j] += a1 * wj[j];
            acc[2][j] += a2 * wj[j];
            acc[3][j] += a3 * wj[j];
        }
    }
    __syncthreads();   // all reads of At/Wt done; union region reusable

    // ---- x -> bf16 tile
#pragma unroll
    for (int i = 0; i < 4; i++)
#pragma unroll
        for (int j = 0; j < 8; j++)
            Ab[(r0 + i) * PADK + c0 + j] = (__bf16)acc[i][j];
    STAGE_W(wqt)
    __syncthreads();

    // ---- phase B: 3 MFMA GEMMs
    const int lane = t & 63;
    const int lr = lane & 15, lg = lane >> 4;
    const int rbase = (t >> 6) * 16;

#define QGEMM(ACC, OUT)                                                                    \
    {                                                                                      \
        f32x4 ACC[8];                                                                      \
        _Pragma("unroll")                                                                  \
        for (int ct = 0; ct < 8; ct++) ACC[ct] = (f32x4){0.f, 0.f, 0.f, 0.f};              \
        _Pragma("unroll")                                                                  \
        for (int kt = 0; kt < 4; kt++) {                                                   \
            const int ko = kt * 32 + 8 * lg;                                               \
            bf16x8 a0 = *(const bf16x8*)&Ab[(rbase + lr) * PADK + ko];                     \
            _Pragma("unroll")                                                              \
            for (int ct = 0; ct < 8; ct++) {                                               \
                bf16x8 bv = *(const bf16x8*)&Wb[(ct * 16 + lr) * PADK + ko];               \
                ACC[ct] = __builtin_amdgcn_mfma_f32_16x16x32_bf16(a0, bv, ACC[ct], 0, 0, 0); \
            }                                                                              \
        }                                                                                  \
        _Pragma("unroll")                                                                  \
        for (int ct = 0; ct < 8; ct++)                                                     \
            _Pragma("unroll")                                                              \
            for (int e = 0; e < 4; e++)                                                    \
                OUT[(size_t)(base + rbase + 4 * lg + e) * 128 + ct * 16 + lr] = ACC[ct][e]; \
    }

    QGEMM(accq, qo)
    __syncthreads();
    STAGE_W(wkt)
    __syncthreads();
    QGEMM(acck, ko)
    __syncthreads();
    STAGE_W(wvt)
    __syncthreads();
    QGEMM(accv, vo)
#undef QGEMM
}

// MFMA K-loop over K=128: contiguous-8-per-lane fragments (m91/m92-verified convention)
#define DO_GEMM(ACC0, ACC1, WPTR)                                                          \
    {                                                                                      \
        _Pragma("unroll")                                                                  \
        for (int kt = 0; kt < 4; kt++) {                                                   \
            const int ko = kt * 32 + 8 * lg;                                               \
            bf16x8 a0 = *(const bf16x8*)&Ab[(rbase + lr) * PADK + ko];                     \
            bf16x8 a1 = *(const bf16x8*)&Ab[(rbase + 16 + lr) * PADK + ko];                \
            _Pragma("unroll")                                                              \
            for (int ct = 0; ct < 8; ct++) {                                               \
                bf16x8 bv = *(const bf16x8*)&WPTR[(ct * 16 + lr) * PADK + ko];             \
                ACC0[ct] = __builtin_amdgcn_mfma_f32_16x16x32_bf16(a0, bv, ACC0[ct], 0, 0, 0); \
                ACC1[ct] = __builtin_amdgcn_mfma_f32_16x16x32_bf16(a1, bv, ACC1[ct], 0, 0, 0); \
            }                                                                              \
        }                                                                                  \
    }

// ---------------------------------------------------------------- fused k3+k4+k5
__global__ __launch_bounds__(256, 2) void k345_kernel(const float* __restrict__ xyz,
                                                      const int* __restrict__ idxw,
                                                      const float* __restrict__ q,
                                                      const float* __restrict__ xk,
                                                      const float* __restrict__ xv,
                                                      const float* __restrict__ d1,
                                                      const float* __restrict__ bd1,
                                                      const float* __restrict__ bd2,
                                                      const float* __restrict__ bg1,
                                                      const float* __restrict__ bg2,
                                                      const __bf16* __restrict__ d2t,
                                                      const __bf16* __restrict__ g1t,
                                                      const __bf16* __restrict__ g2t,
                                                      float* __restrict__ attn,
                                                      float* __restrict__ res_pre) {
    __shared__ __bf16 Ab[128 * PADK];
    __shared__ __bf16 Wb[128 * PADK];
    __shared__ float rels[128 * 4];
    __shared__ int jrow[128];
    __shared__ float d1s[3 * 128];
    __shared__ float bd1s[128], bd2s[128], bg1s[128], bg2s[128];

    const int t = threadIdx.x;
    const int wv = t >> 6;
    const int lane = t & 63;
    const int lr = lane & 15, lg = lane >> 4;
    const int R0 = blockIdx.x * 128;
    const int b = R0 >> 17;
    const int rbase = wv * 32;

#pragma unroll
    for (int e = 0; e < 2; e++) { int id = t + e * 256; if (id < 384) d1s[id] = d1[id]; }
    if (t < 128) {
        bd1s[t] = bd1[t]; bd2s[t] = bd2[t]; bg1s[t] = bg1[t]; bg2s[t] = bg2[t];
    } else {
        int r = t - 128;
        int j = idxw[R0 + r];
        jrow[r] = j;
        const float* pn = xyz + (size_t)((R0 + r) >> 4) * 3;
        const float* pj = xyz + (size_t)((b << 13) + j) * 3;
        rels[r * 4 + 0] = pn[0] - pj[0];
        rels[r * 4 + 1] = pn[1] - pj[1];
        rels[r * 4 + 2] = pn[2] - pj[2];
    }
    STAGE_W(d2t)
    __syncthreads();

    // T = relu(rel@d1 + bd1) -> Ab (bf16)
    {
        const int c = t & 127;
        const float w0 = d1s[c], w1 = d1s[128 + c], w2 = d1s[256 + c], bb = bd1s[c];
#pragma unroll
        for (int e = 0; e < 64; e++) {
            int r = (t >> 7) + e * 2;
            float v = fmaf(rels[r * 4 + 2], w2,
                      fmaf(rels[r * 4 + 1], w1, fmaf(rels[r * 4 + 0], w0, bb)));
            Ab[r * PADK + c] = (__bf16)fmaxf(v, 0.0f);
        }
    }
    __syncthreads();

    // GEMM1: pos = relu(T@d2 + bd2), kept in registers for h AND the value path
    f32x4 acc0[8], acc1[8];
#pragma unroll
    for (int ct = 0; ct < 8; ct++) {
        float bb = bd2s[ct * 16 + lr];
        acc0[ct] = (f32x4){bb, bb, bb, bb};
        acc1[ct] = acc0[ct];
    }
    DO_GEMM(acc0, acc1, Wb)
    f32x4 pos0[8], pos1[8];
#pragma unroll
    for (int ct = 0; ct < 8; ct++) {
#pragma unroll
        for (int e = 0; e < 4; e++) {
            pos0[ct][e] = fmaxf(acc0[ct][e], 0.0f);
            pos1[ct][e] = fmaxf(acc1[ct][e], 0.0f);
        }
    }

    // h = pos + q - k_nbr  -> Ab (bf16)   [own rows only]
#pragma unroll
    for (int rt = 0; rt < 2; rt++) {
        const int rloc = rbase + rt * 16 + 4 * lg;
        const size_t qbase = (size_t)((R0 + rloc) >> 4) * 128;
        const int j0 = jrow[rloc + 0], j1 = jrow[rloc + 1];
        const int j2 = jrow[rloc + 2], j3 = jrow[rloc + 3];
        const size_t kb0 = (size_t)((b << 13) + j0) * 128;
        const size_t kb1 = (size_t)((b << 13) + j1) * 128;
        const size_t kb2 = (size_t)((b << 13) + j2) * 128;
        const size_t kb3 = (size_t)((b << 13) + j3) * 128;
        f32x4* posR = rt ? pos1 : pos0;
#pragma unroll
        for (int ct = 0; ct < 8; ct++) {
            const int c = ct * 16 + lr;
            const float qv = q[qbase + c];
            f32x4 p = posR[ct];
            Ab[(rloc + 0) * PADK + c] = (__bf16)(p[0] + qv - xk[kb0 + c]);
            Ab[(rloc + 1) * PADK + c] = (__bf16)(p[1] + qv - xk[kb1 + c]);
            Ab[(rloc + 2) * PADK + c] = (__bf16)(p[2] + qv - xk[kb2 + c]);
            Ab[(rloc + 3) * PADK + c] = (__bf16)(p[3] + qv - xk[kb3 + c]);
        }
    }
    __syncthreads();
    STAGE_W(g1t)
    __syncthreads();

    // GEMM2: u = relu(h@g1 + bg1) -> Ab (bf16)
#pragma unroll
    for (int ct = 0; ct < 8; ct++) {
        float bb = bg1s[ct * 16 + lr];
        acc0[ct] = (f32x4){bb, bb, bb, bb};
        acc1[ct] = acc0[ct];
    }
    DO_GEMM(acc0, acc1, Wb)
#pragma unroll
    for (int rt = 0; rt < 2; rt++) {
        const int rloc = rbase + rt * 16 + 4 * lg;
        f32x4* accR = rt ? acc1 : acc0;
#pragma unroll
        for (int ct = 0; ct < 8; ct++) {
            const int c = ct * 16 + lr;
            f32x4 p = accR[ct];
            Ab[(rloc + 0) * PADK + c] = (__bf16)fmaxf(p[0], 0.0f);
            Ab[(rloc + 1) * PADK + c] = (__bf16)fmaxf(p[1], 0.0f);
            Ab[(rloc + 2) * PADK + c] = (__bf16)fmaxf(p[2], 0.0f);
            Ab[(rloc + 3) * PADK + c] = (__bf16)fmaxf(p[3], 0.0f);
        }
    }
    __syncthreads();
    STAGE_W(g2t)
    __syncthreads();

    // GEMM3: logits = u@g2 + bg2 ; softmax over 16 neighbors ;
    // then res_pre = sum_k attn*(v+pos)
#pragma unroll
    for (int ct = 0; ct < 8; ct++) {
        float bb = bg2s[ct * 16 + lr];
        acc0[ct] = (f32x4){bb, bb, bb, bb};
        acc1[ct] = acc0[ct];
    }
    DO_GEMM(acc0, acc1, Wb)
    const float scale = 0.08838834764831845f; /* 1/sqrt(128) */
#pragma unroll
    for (int rt = 0; rt < 2; rt++) {
        const int rloc = rbase + rt * 16 + 4 * lg;
        const int j0 = jrow[rloc + 0], j1 = jrow[rloc + 1];
        const int j2 = jrow[rloc + 2], j3 = jrow[rloc + 3];
        const size_t vb0 = (size_t)((b << 13) + j0) * 128;
        const size_t vb1 = (size_t)((b << 13) + j1) * 128;
        const size_t vb2 = (size_t)((b << 13) + j2) * 128;
        const size_t vb3 = (size_t)((b << 13) + j3) * 128;
        f32x4* accR = rt ? acc1 : acc0;
        f32x4* posR = rt ? pos1 : pos0;
#pragma unroll
        for (int ct = 0; ct < 8; ct++) {
            const int c = ct * 16 + lr;
            f32x4 p = accR[ct];
            float l0 = p[0] * scale, l1 = p[1] * scale, l2 = p[2] * scale, l3 = p[3] * scale;
            float m = fmaxf(fmaxf(l0, l1), fmaxf(l2, l3));
            m = fmaxf(m, __shfl_xor(m, 16));
            m = fmaxf(m, __shfl_xor(m, 32));
            float e0 = __expf(l0 - m), e1 = __expf(l1 - m);
            float e2 = __expf(l2 - m), e3 = __expf(l3 - m);
            float s = (e0 + e1) + (e2 + e3);
            s += __shfl_xor(s, 16);
            s += __shfl_xor(s, 32);
            float inv = 1.0f / s;
            float a0 = e0 * inv, a1 = e1 * inv, a2 = e2 * inv, a3 = e3 * inv;
            size_t ob = (size_t)(R0 + rloc) * 128 + c;
            attn[ob + 0 * 128] = a0;
            attn[ob + 1 * 128] = a1;
            attn[ob + 2 * 128] = a2;
            attn[ob + 3 * 128] = a3;
            f32x4 pp = posR[ct];
            float r = a0 * (xv[vb0 + c] + pp[0])
                    + a1 * (xv[vb1 + c] + pp[1])
                    + a2 * (xv[vb2 + c] + pp[2])
                    + a3 * (xv[vb3 + c] + pp[3]);
            r += __shfl_xor(r, 16);
            r += __shfl_xor(r, 32);
            if (lg == 0)
                res_pre[(size_t)((R0 >> 4) + wv * 2 + rt) * 128 + c] = r;
        }
    }
}

// ---------------------------------------------------------------- res = res_pre@fc2 + b + features
__global__ __launch_bounds__(256, 1) void k6_kernel(const float* __restrict__ res_pre,
                                                    const float* __restrict__ w,
                                                    const float* __restrict__ bias,
                                                    const float* __restrict__ feats,
                                                    float* __restrict__ res_out) {
    __shared__ float At[128 * 65];
    __shared__ __align__(16) float Wt[128 * 64];
    const int t = threadIdx.x;
    const int base = blockIdx.x * 64;
#pragma unroll
    for (int e = 0; e < 32; e++) {
        int id = t + e * 256;
        int r = id >> 7, c = id & 127;
        At[c * 65 + r] = res_pre[(size_t)(base + r) * 128 + c];
    }
#pragma unroll
    for (int e = 0; e < 32; e++) { int id = t + e * 256; Wt[id] = w[id]; }
    __syncthreads();
    const int r0 = (t >> 4) * 4;
    const int c0 = (t & 15) * 4;
    float acc[4][4];
#pragma unroll
    for (int i = 0; i < 4; i++)
#pragma unroll
        for (int j = 0; j < 4; j++) acc[i][j] = bias[c0 + j];
#pragma unroll 4
    for (int kk = 0; kk < 128; ++kk) {
        float a0 = At[kk * 65 + r0 + 0];
        float a1 = At[kk * 65 + r0 + 1];
        float a2 = At[kk * 65 + r0 + 2];
        float a3 = At[kk * 65 + r0 + 3];
        const float4 w0 = *(const float4*)&Wt[kk * 64 + c0];
        float wj[4] = {w0.x, w0.y, w0.z, w0.w};
#pragma unroll
        for (int j = 0; j < 4; j++) {
            acc[0][j] += a0 * wj[j];
            acc[1][j] += a1 * wj[j];
            acc[2][j] += a2 * wj[j];
            acc[3][j] += a3 * wj[j];
        }
    }
#pragma unroll
    for (int i = 0; i < 4; i++)
#pragma unroll
        for (int j = 0; j < 4; j++)
            res_out[(size_t)(base + r0 + i) * 64 + c0 + j] =
                acc[i][j] + feats[(size_t)(base + r0 + i) * 64 + c0 + j];
}

extern "C" void kernel_launch(void* const* d_in, const int* in_sizes, int n_in,
                              void* d_out, int out_size, void* d_ws, size_t ws_size,
                              hipStream_t stream) {
    (void)in_sizes; (void)n_in; (void)out_size; (void)ws_size;
    const float* xyz   = (const float*)d_in[0];
    const float* feats = (const float*)d_in[2];
    const float* fc1_w = (const float*)d_in[3];
    const float* fc1_b = (const float*)d_in[4];
    const float* fc2_w = (const float*)d_in[5];
    const float* fc2_b = (const float*)d_in[6];
    const float* g1    = (const float*)d_in[7];
    const float* bg1   = (const float*)d_in[8];
    const float* g2    = (const float*)d_in[9];
    const float* bg2   = (const float*)d_in[10];
    const float* d1    = (const float*)d_in[11];
    const float* bd1   = (const float*)d_in[12];
    const float* d2    = (const float*)d_in[13];
    const float* bd2   = (const float*)d_in[14];
    const float* wq    = (const float*)d_in[15];
    const float* wk    = (const float*)d_in[16];
    const float* wv    = (const float*)d_in[17];

    int* idxw   = (int*)d_ws;
    float* qbuf = (float*)((char*)d_ws + (1 << 20));
    float* kbuf = qbuf + 2097152;
    float* vbuf = kbuf + 2097152;
    float* rpre = vbuf + 2097152;
    __bf16* d2t = (__bf16*)(rpre + 2097152);
    __bf16* g1t = d2t + 16384;
    __bf16* g2t = g1t + 16384;
    __bf16* wqt = g2t + 16384;
    __bf16* wkt = wqt + 16384;
    __bf16* wvt = wkt + 16384;

    float* res_out = (float*)d_out;
    float* attn    = res_out + 1048576;

    wprep_kernel<<<6, 256, 0, stream>>>(d2, g1, g2, wq, wk, wv,
                                        d2t, g1t, g2t, wqt, wkt, wvt);
    knn_kernel<<<4096, 256, 0, stream>>>(xyz, idxw);
    xqkv_kernel<<<256, 256, 0, stream>>>(feats, fc1_w, fc1_b, wqt, wkt, wvt,
                                         qbuf, kbuf, vbuf);
    k345_kernel<<<2048, 256, 0, stream>>>(xyz, idxw, qbuf, kbuf, vbuf, d1, bd1, bd2, bg1, bg2,
                                          d2t, g1t, g2t, attn, rpre);
    k6_kernel<<<256, 256, 0, stream>>>(rpre, fc2_w, fc2_b, feats, res_out);
}